// Round 4
// baseline (198.022 us; speedup 1.0000x reference)
//
#include <hip/hip_runtime.h>

// Problem constants (from reference): N=1e6, D1=D2=16, NC=64 outer, NCPC=8 inner.
constexpr int D = 16;
constexpr int NC = 64;
constexpr int NCPC = 8;
constexpr int OSTRIDE = NCPC * D + 4;   // 132 floats: pad 4 so start bank = (4*o)%32, 16B aligned
constexpr int NPT = 2;                  // points per thread
constexpr int BLOCK = 512;

// R2 post-mortem: 2nd arg behaves as min BLOCKS/CU on this toolchain (VGPR=32 at
// (512,8) proved it). (512,2) -> VGPR cap 128: no spill risk; compiler lands where
// it lands, LDS (36.1KB) allows up to 4 blocks/CU if VGPR <= 64.
__global__ __launch_bounds__(BLOCK, 2)
void cluster_kernel(const float* __restrict__ x,
                    const float* __restrict__ co,
                    const float* __restrict__ ci,
                    int* __restrict__ out, int n)
{
    // R4: s_onorm removed from LDS. Outer-center norms now live one-per-lane in a
    // VGPR (my_norm, center index = lane) and are fetched with v_readlane (j is a
    // compile-time constant) -> the outer loop has NO ds_read mixed into the s_load
    // stream, so lgkmcnt stays a pure SMEM counter and the compiler can pipeline
    // center s_loads instead of draining lgkmcnt(0) at every norm read.
    __shared__ __align__(16) float s_ci[NC * OSTRIDE];
    __shared__ float s_inorm[NC * 9];            // [o][k], stride 9 to spread banks

    const int t = threadIdx.x;

    // ---- Block setup: stage inner centers (8192 floats = 2048 float4) into LDS ----
    const float4* ci4 = (const float4*)ci;
    #pragma unroll
    for (int i = 0; i < (NC * NCPC * D / 4) / BLOCK; ++i) {   // 4 iters at BLOCK=512
        int idx = t + i * BLOCK;        // 0..2047
        int o = idx >> 5;               // 32 float4 per outer cluster
        int f = idx & 31;               // k*4 + d4
        float4 v = ci4[idx];
        *(float4*)&s_ci[o * OSTRIDE + f * 4] = v;
    }
    // ---- 512 inner norms, one per thread, once per block ----
    for (int i = t; i < NC * NCPC; i += BLOCK) {
        const float* src = ci + i * D;
        float s = 0.f;
        #pragma unroll
        for (int k = 0; k < D; ++k) s = fmaf(src[k], src[k], s);
        s_inorm[(i >> 3) * 9 + (i & 7)] = s;
    }
    // ---- Outer norm for center (t&63), held in a register for the whole kernel ----
    float my_norm;
    {
        const float* c = co + (t & 63) * D;
        float s = 0.f;
        #pragma unroll
        for (int k = 0; k < D; ++k) s = fmaf(c[k], c[k], s);
        my_norm = s;
    }
    __syncthreads();

    const int base = blockIdx.x * (BLOCK * NPT) + t;
    #pragma unroll 1                       // keep body in I-cache
    for (int it = 0; it < NPT; ++it) {
        int p = base + it * BLOCK;
        if (p < n) {
            const float4* xp = (const float4*)(x + (size_t)p * 32);
            // Load only x1 now; x2 loads deferred past the outer argmin so the
            // two 16-float arrays are never simultaneously live.
            float4 xa = xp[0], xb = xp[1], xc = xp[2], xd = xp[3];
            float x1[16] = {xa.x,xa.y,xa.z,xa.w, xb.x,xb.y,xb.z,xb.w,
                            xc.x,xc.y,xc.z,xc.w, xd.x,xd.y,xd.z,xd.w};

            // ---- Outer argmin: d = ||c_j||^2 - 2 x1.c_j ; centers via wave-uniform
            //      global access -> s_load_dwordx16 (constant cache); norm via
            //      v_readlane (no LDS in this loop). Arithmetic identical to R0. ----
            float bestd = 3.4e38f;
            int bo = 0;
            #pragma unroll
            for (int j = 0; j < NC; ++j) {
                const float* c = co + j * D;
                float dot = 0.f;
                #pragma unroll
                for (int k = 0; k < D; ++k) dot = fmaf(x1[k], c[k], dot);
                float nj = __int_as_float(
                    __builtin_amdgcn_readlane(__float_as_int(my_norm), j));
                float d = fmaf(-2.f, dot, nj);
                if (d < bestd) { bestd = d; bo = j; }   // strict < : first index wins
            }

            // ---- Now load x2 (x1 registers dead -> reusable) ----
            float4 ya = xp[4], yb = xp[5], yc = xp[6], yd = xp[7];
            float x2[16] = {ya.x,ya.y,ya.z,ya.w, yb.x,yb.y,yb.z,yb.w,
                            yc.x,yc.y,yc.z,yc.w, yd.x,yd.y,yd.z,yd.w};

            // ---- Inner argmin over the 8 sub-centers of bo (LDS gather, pure DS) ----
            const float* cb = s_ci + bo * OSTRIDE;
            const float* nb = s_inorm + bo * 9;
            float bestd2 = 3.4e38f;
            int bk = 0;
            #pragma unroll
            for (int k = 0; k < NCPC; ++k) {
                float4 c0 = *(const float4*)&cb[k * D + 0];
                float4 c1 = *(const float4*)&cb[k * D + 4];
                float4 c2 = *(const float4*)&cb[k * D + 8];
                float4 c3 = *(const float4*)&cb[k * D + 12];
                float dot = 0.f;
                dot = fmaf(x2[0],  c0.x, dot); dot = fmaf(x2[1],  c0.y, dot);
                dot = fmaf(x2[2],  c0.z, dot); dot = fmaf(x2[3],  c0.w, dot);
                dot = fmaf(x2[4],  c1.x, dot); dot = fmaf(x2[5],  c1.y, dot);
                dot = fmaf(x2[6],  c1.z, dot); dot = fmaf(x2[7],  c1.w, dot);
                dot = fmaf(x2[8],  c2.x, dot); dot = fmaf(x2[9],  c2.y, dot);
                dot = fmaf(x2[10], c2.z, dot); dot = fmaf(x2[11], c2.w, dot);
                dot = fmaf(x2[12], c3.x, dot); dot = fmaf(x2[13], c3.y, dot);
                dot = fmaf(x2[14], c3.z, dot); dot = fmaf(x2[15], c3.w, dot);
                float d = fmaf(-2.f, dot, nb[k]);
                if (d < bestd2) { bestd2 = d; bk = k; }
            }

            out[p] = bo * NCPC + bk;
        }
    }
}

extern "C" void kernel_launch(void* const* d_in, const int* in_sizes, int n_in,
                              void* d_out, int out_size, void* d_ws, size_t ws_size,
                              hipStream_t stream) {
    const float* x  = (const float*)d_in[0];   // (N, 32) fp32
    const float* co = (const float*)d_in[1];   // (64, 16) fp32
    const float* ci = (const float*)d_in[2];   // (64, 8, 16) fp32
    int* out = (int*)d_out;                    // (N,) int32
    int n = in_sizes[0] / 32;
    int blocks = (n + BLOCK * NPT - 1) / (BLOCK * NPT);
    cluster_kernel<<<blocks, BLOCK, 0, stream>>>(x, co, ci, out, n);
}